// Round 18
// baseline (238.335 us; speedup 1.0000x reference)
//
#include <hip/hip_runtime.h>
#include <cstdint>

#define F_IN  128
#define F_HID 16
#define F_OUT 138
#define NBUCK 512        // dst buckets
#define NPB_SHIFT 8
#define NPB 256          // nodes per bucket
#define NB  512          // edge slabs for binning passes
#define SLAB_CAP 12544   // >= ceil(E/NB) = 12500
#define STAGE_CAP 18432  // >= max bucket edges (~16.4k avg + slack)
#define OUT_NV 16        // nodes per k_out block

typedef float f32x8 __attribute__((ext_vector_type(8)));
typedef int   i32x4 __attribute__((ext_vector_type(4)));
typedef _Float16 h16;
typedef _Float16 h16x8 __attribute__((ext_vector_type(8)));   // 16 B

// ---------------------------------------------------------------------------
// Inline edge_index dtype detection: int64 (LE, values < 2^31) -> every odd
// int32 word is zero. Returns 2 (int64 stride in words) or 1 (int32).
__device__ __forceinline__ int edge_mult(const int* __restrict__ idx) {
    int nz = 0;
#pragma unroll
    for (int i = 1; i < 64; i += 2) nz |= idx[i];
    return nz ? 1 : 2;
}

// Pass A: per-slab LDS histogram of dst-buckets (reads dst only).
__global__ void __launch_bounds__(1024, 8)
k_bincount(const int* __restrict__ idx, unsigned* __restrict__ cnt, int E) {
    __shared__ unsigned hist[NBUCK];
    int tid = threadIdx.x;
    if (tid < NBUCK) hist[tid] = 0;
    __syncthreads();
    const int mult = edge_mult(idx);
    int slab = (E + NB - 1) / NB;
    int start = blockIdx.x * slab, end = min(E, start + slab);
    if (mult == 2) {
        for (int e = start + tid; e < end; e += 1024)
            atomicAdd(&hist[((const int2*)idx)[(size_t)E + e].x >> NPB_SHIFT], 1u);
    } else {
        for (int e = start + tid; e < end; e += 1024)
            atomicAdd(&hist[idx[(size_t)E + e] >> NPB_SHIFT], 1u);
    }
    __syncthreads();
    if (tid < NBUCK) cnt[(size_t)tid * NB + blockIdx.x] = hist[tid];
}

// Scan step 1: one block per bucket; exclusive-scan its NB slab counts in
// place (pair-per-thread Hillis-Steele); emit bucket total.
__global__ void k_scanA(unsigned* __restrict__ cnt, unsigned* __restrict__ bucketTot) {
    __shared__ unsigned sh[256];
    int t = threadIdx.x;
    unsigned* row = cnt + (size_t)blockIdx.x * NB;
    unsigned e0 = row[2 * t], e1 = row[2 * t + 1];
    unsigned pair = e0 + e1;
    sh[t] = pair;
    __syncthreads();
    for (int off = 1; off < 256; off <<= 1) {
        unsigned v = (t >= off) ? sh[t - off] : 0u;
        __syncthreads();
        sh[t] += v;
        __syncthreads();
    }
    unsigned excl = sh[t] - pair;
    row[2 * t] = excl;
    row[2 * t + 1] = excl + e0;
    if (t == 255) bucketTot[blockIdx.x] = sh[255];
}

// Scan step 2: one block (512 threads); exclusive scan of bucket totals.
__global__ void k_scanB(const unsigned* __restrict__ bucketTot,
                        unsigned* __restrict__ bucketPtr) {
    __shared__ unsigned sh[NBUCK];
    int t = threadIdx.x;
    unsigned c = bucketTot[t];
    sh[t] = c;
    __syncthreads();
    for (int off = 1; off < NBUCK; off <<= 1) {
        unsigned v = (t >= off) ? sh[t - off] : 0u;
        __syncthreads();
        sh[t] += v;
        __syncthreads();
    }
    bucketPtr[t] = sh[t] - c;          // exclusive
    if (t == NBUCK - 1) bucketPtr[NBUCK] = sh[t];
}

// Pass B with LDS write-combining, 1024 threads: histogram slab by bucket,
// scan, scatter the slab's edges into LDS staging sorted by bucket, then
// 16-lane-group copy-out to each (slab,bucket) global segment (~24 entries).
// Packed entry: (dstLocal<<17) | src  (8+17 = 25 bits, src < 2^17).
__global__ void __launch_bounds__(1024, 8)
k_binfill(const int* __restrict__ idx,
          const unsigned* __restrict__ cnt,
          const unsigned* __restrict__ bucketPtr,
          unsigned* __restrict__ binned, int E) {
    __shared__ unsigned hist[NBUCK];
    __shared__ unsigned sofs[NBUCK];
    __shared__ unsigned scur[NBUCK];
    __shared__ unsigned stage[SLAB_CAP];   // 50 KB
    int tid = threadIdx.x;
    if (tid < NBUCK) hist[tid] = 0;
    __syncthreads();
    const int mult = edge_mult(idx);
    int slab = (E + NB - 1) / NB;
    int start = blockIdx.x * slab, end = min(E, start + slab);
    // phase 1: histogram (dst only)
    if (mult == 2) {
        for (int e = start + tid; e < end; e += 1024)
            atomicAdd(&hist[((const int2*)idx)[(size_t)E + e].x >> NPB_SHIFT], 1u);
    } else {
        for (int e = start + tid; e < end; e += 1024)
            atomicAdd(&hist[idx[(size_t)E + e] >> NPB_SHIFT], 1u);
    }
    __syncthreads();
    // phase 2: exclusive scan of NBUCK counts (Hillis-Steele on tid<NBUCK)
    if (tid < NBUCK) scur[tid] = hist[tid];
    __syncthreads();
    for (int off = 1; off < NBUCK; off <<= 1) {
        unsigned v = 0;
        if (tid < NBUCK && tid >= off) v = scur[tid - off];
        __syncthreads();
        if (tid < NBUCK) scur[tid] += v;
        __syncthreads();
    }
    if (tid < NBUCK) {
        unsigned ex = scur[tid] - hist[tid];
        sofs[tid] = ex;
        scur[tid] = ex;
    }
    __syncthreads();
    // phase 3: scatter slab edges into LDS staging sorted by bucket
    for (int e = start + tid; e < end; e += 1024) {
        int s, d;
        if (mult == 2) { s = ((const int2*)idx)[e].x; d = ((const int2*)idx)[(size_t)E + e].x; }
        else           { s = idx[e];                  d = idx[(size_t)E + e]; }
        unsigned pos = atomicAdd(&scur[d >> NPB_SHIFT], 1u);
        stage[pos] = ((unsigned)(d & (NPB - 1)) << 17) | (unsigned)s;
    }
    __syncthreads();
    // phase 4: copy-out, one 16-lane group per bucket segment
    int g = tid >> 4, lane = tid & 15;       // 64 groups
    for (int b = g; b < NBUCK; b += 64) {
        unsigned s0 = sofs[b], len = scur[b] - s0;
        if (len == 0) continue;
        unsigned gbase = cnt[(size_t)b * NB + blockIdx.x] + bucketPtr[b];
        for (unsigned i = lane; i < len; i += 16)
            binned[gbase + i] = stage[s0 + i];
    }
}

// Fused per-bucket (1024 threads): degree histogram -> scan -> ptr + dinv,
// then sort the bucket's edges into LDS staging by node and stream out
// col[] as one coalesced sequential copy (fallback: direct scatter).
__global__ void __launch_bounds__(1024, 8)
k_ptrfill(const unsigned* __restrict__ bucketPtr,
          const unsigned* __restrict__ binned,
          unsigned* __restrict__ p0,
          float* __restrict__ dinv, int* __restrict__ col,
          int n, int E) {
    __shared__ unsigned deg[NPB];
    __shared__ unsigned cur[NPB];
    __shared__ unsigned sh[NPB];
    __shared__ unsigned stage[STAGE_CAP];   // 72 KB
    int tid = threadIdx.x, bb = blockIdx.x;
    if (tid < NPB) deg[tid] = 0;
    __syncthreads();
    unsigned start = bucketPtr[bb], end = bucketPtr[bb + 1];
    unsigned cntE = end - start;
    for (unsigned i = start + tid; i < end; i += 1024)
        atomicAdd(&deg[binned[i] >> 17], 1u);
    __syncthreads();
    unsigned d0 = 0;
    if (tid < NPB) { d0 = deg[tid]; sh[tid] = d0; }
    __syncthreads();
    for (int off = 1; off < NPB; off <<= 1) {
        unsigned v = 0;
        if (tid < NPB && tid >= off) v = sh[tid - off];
        __syncthreads();
        if (tid < NPB) sh[tid] += v;
        __syncthreads();
    }
    if (tid < NPB) {
        unsigned lbase = sh[tid] - d0;        // exclusive prefix (local)
        cur[tid] = lbase;
        int v = (bb << NPB_SHIFT) + tid;
        if (v < n) {
            p0[v] = start + lbase;
            dinv[v] = rsqrtf((float)(d0 + 1u));   // +1 self-loop
        }
    }
    if (bb == 0 && tid == 0) p0[n] = (unsigned)E;
    __syncthreads();
    if (cntE <= STAGE_CAP) {
        for (unsigned i = start + tid; i < end; i += 1024) {
            unsigned entry = binned[i];
            unsigned pos = atomicAdd(&cur[entry >> 17], 1u);
            stage[pos] = entry & 0x1FFFFu;
        }
        __syncthreads();
        for (unsigned i = tid; i < cntE; i += 1024)
            col[start + i] = (int)stage[i];
    } else {
        for (unsigned i = start + tid; i < end; i += 1024) {
            unsigned entry = binned[i];
            unsigned pos = atomicAdd(&cur[entry >> 17], 1u);
            col[start + pos] = (int)(entry & 0x1FFFFu);
        }
    }
}

// g1[v][j] = dinv[v] * (x[v] . W1[:,j]), stored as fp16 (gather table is
// then 3.2 MB -> fits one XCD's 4 MB L2). 16 nodes x 16 feats per block.
__global__ void k_gemm1(const float* __restrict__ x, const float* __restrict__ W1,
                        const float* __restrict__ dinv,
                        h16* __restrict__ g1, int n) {
    __shared__ float w1s[F_IN * F_HID];     // 8 KB
    __shared__ float xs[16][F_IN + 4];
    int tid = threadIdx.x;
    for (int i = tid; i < F_IN * F_HID; i += 256) w1s[i] = W1[i];
    int nb = blockIdx.x * 16;
    for (int q = tid; q < 512; q += 256) {
        int r = q >> 5, k4 = q & 31;
        int g = nb + r;
        float4 v = make_float4(0.f, 0.f, 0.f, 0.f);
        if (g < n) v = ((const float4*)x)[(size_t)g * 32 + k4];
        xs[r][k4 * 4 + 0] = v.x; xs[r][k4 * 4 + 1] = v.y;
        xs[r][k4 * 4 + 2] = v.z; xs[r][k4 * 4 + 3] = v.w;
    }
    __syncthreads();
    int r = tid >> 4, j = tid & 15;
    int g = nb + r;
    if (g < n) {
        float acc = 0.f;
#pragma unroll
        for (int k = 0; k < F_IN; ++k) acc += xs[r][k] * w1s[k * F_HID + j];
        g1[(size_t)g * F_HID + j] = (h16)(acc * dinv[g]);
    }
}

// Pull-mode CSR aggregation, 8 threads/node (sub = 0..7), each thread
// handling the FULL 32 B fp16 row for its deg/8 edge chunk:
//  - col loaded as int4 (4 edges per transaction, was 1) with scalar
//    head/tail for 16 B alignment
//  - both row halves gathered by the same thread (kills the 2x duplicate
//    col loads of the q-split layout)
// => 2.25 scattered L1 transactions/edge vs 4 before (L1-rate bound).
// Partials combined via __shfl_xor masks 1,2,4; sub==0 adds self-loop,
// applies epilogue, stores fp16.
template <int RELU>
__global__ void __launch_bounds__(256)
k_agg(const unsigned* __restrict__ p0, const int* __restrict__ col,
      const h16x8* __restrict__ gin8, h16x8* __restrict__ gout8,
      const float* __restrict__ dinv, const float* __restrict__ b1, int n) {
    int t = blockIdx.x * blockDim.x + threadIdx.x;
    int v = t >> 3;
    int sub = t & 7;
    if (v >= n) return;
    unsigned rs = p0[v], re = p0[v + 1];
    unsigned deg = re - rs;
    unsigned chunk = (deg + 7) >> 3;
    unsigned cs = rs + sub * chunk;
    unsigned ce = min(re, cs + chunk);
    if (cs > re) cs = re;
    f32x8 acc0 = (f32x8)0.f, acc1 = (f32x8)0.f;
    unsigned i = cs;
    // scalar head until col+i is 16B-aligned (col base is 16B-aligned)
    for (; i < ce && (i & 3u); ++i) {
        int u = __builtin_nontemporal_load(col + i);
        acc0 += __builtin_convertvector(gin8[(size_t)u * 2], f32x8);
        acc1 += __builtin_convertvector(gin8[(size_t)u * 2 + 1], f32x8);
    }
    for (; i + 4 <= ce; i += 4) {
        i32x4 u = __builtin_nontemporal_load((const i32x4*)(col + i));
        h16x8 a0 = gin8[(size_t)u[0] * 2], b0 = gin8[(size_t)u[0] * 2 + 1];
        h16x8 a1 = gin8[(size_t)u[1] * 2], b1v = gin8[(size_t)u[1] * 2 + 1];
        h16x8 a2 = gin8[(size_t)u[2] * 2], b2v = gin8[(size_t)u[2] * 2 + 1];
        h16x8 a3 = gin8[(size_t)u[3] * 2], b3v = gin8[(size_t)u[3] * 2 + 1];
        f32x8 s0 = __builtin_convertvector(a0, f32x8) + __builtin_convertvector(a1, f32x8);
        f32x8 s1 = __builtin_convertvector(a2, f32x8) + __builtin_convertvector(a3, f32x8);
        f32x8 r0 = __builtin_convertvector(b0, f32x8) + __builtin_convertvector(b1v, f32x8);
        f32x8 r1 = __builtin_convertvector(b2v, f32x8) + __builtin_convertvector(b3v, f32x8);
        acc0 += s0 + s1;
        acc1 += r0 + r1;
    }
    for (; i < ce; ++i) {
        int u = __builtin_nontemporal_load(col + i);
        acc0 += __builtin_convertvector(gin8[(size_t)u * 2], f32x8);
        acc1 += __builtin_convertvector(gin8[(size_t)u * 2 + 1], f32x8);
    }
    // combine 8 sub-partials (lane bits 0,1,2 within the node's lane group)
#pragma unroll
    for (int k = 0; k < 8; ++k) {
        acc0[k] += __shfl_xor((float)acc0[k], 1);
        acc1[k] += __shfl_xor((float)acc1[k], 1);
    }
#pragma unroll
    for (int k = 0; k < 8; ++k) {
        acc0[k] += __shfl_xor((float)acc0[k], 2);
        acc1[k] += __shfl_xor((float)acc1[k], 2);
    }
#pragma unroll
    for (int k = 0; k < 8; ++k) {
        acc0[k] += __shfl_xor((float)acc0[k], 4);
        acc1[k] += __shfl_xor((float)acc1[k], 4);
    }
    if (sub == 0) {
        size_t o = (size_t)v * 2;
        acc0 += __builtin_convertvector(gin8[o], f32x8);       // self-loop
        acc1 += __builtin_convertvector(gin8[o + 1], f32x8);
        float di = dinv[v];
        f32x8 r0, r1;
        if (RELU) {
#pragma unroll
            for (int k = 0; k < 8; ++k) {
                r0[k] = fmaxf(di * acc0[k] + b1[k], 0.f) * di;
                r1[k] = fmaxf(di * acc1[k] + b1[k + 8], 0.f) * di;
            }
        } else {
            r0 = acc0 * di;
            r1 = acc1 * di;
        }
        gout8[o]     = __builtin_convertvector(r0, h16x8);   // cached: next pass reads
        gout8[o + 1] = __builtin_convertvector(r1, h16x8);
    }
}

// Node-tiled output GEMM: block owns OUT_NV contiguous nodes; fp16 B rows
// staged once in LDS as fp32, outputs written coalesced NT.
// out[v][c] = B[v] . W2[:,c] + b2[c]   (dinv already folded into B)
__global__ void __launch_bounds__(256)
k_out(const h16* __restrict__ B,
      const float* __restrict__ W2, const float* __restrict__ b2,
      float* __restrict__ out, int n) {
    __shared__ float w2s[F_HID * F_OUT];   // 8.8 KB
    __shared__ float b2s[F_OUT];
    __shared__ float Bs[OUT_NV][F_HID];    // 1 KB
    int tid = threadIdx.x;
    for (int i = tid; i < F_HID * F_OUT; i += 256) w2s[i] = W2[i];
    if (tid < F_OUT) b2s[tid] = b2[tid];
    int vbase = blockIdx.x * OUT_NV;
    {
        int vl = tid >> 4, j = tid & 15;
        int v = vbase + vl;
        Bs[vl][j] = (v < n) ? (float)B[(size_t)v * F_HID + j] : 0.f;
    }
    __syncthreads();
    const int total = OUT_NV * F_OUT;   // 2208
    for (int q = tid; q < total; q += 256) {
        int vl = q / F_OUT, c = q - vl * F_OUT;
        int v = vbase + vl;
        if (v >= n) continue;
        float acc = b2s[c];
#pragma unroll
        for (int j = 0; j < F_HID; ++j) acc += Bs[vl][j] * w2s[j * F_OUT + c];
        __builtin_nontemporal_store(acc, out + (size_t)v * F_OUT + c);
    }
}

extern "C" void kernel_launch(void* const* d_in, const int* in_sizes, int n_in,
                              void* d_out, int out_size, void* d_ws, size_t ws_size,
                              hipStream_t stream) {
    const float* x   = (const float*)d_in[0];
    const int*   idx = (const int*)d_in[1];
    const float* W1  = (const float*)d_in[2];
    const float* b1  = (const float*)d_in[3];
    const float* W2  = (const float*)d_in[4];
    const float* b2  = (const float*)d_in[5];
    float* out = (float*)d_out;

    const int n = in_sizes[0] / F_IN;       // 100000
    const int E = in_sizes[1] / 2;          // 6400000

    char* ws = (char*)d_ws;
    size_t off = 0;
    auto carve = [&](size_t bytes) { char* p = ws + off; off += (bytes + 255) / 256 * 256; return p; };
    float*    dinv      = (float*)carve((size_t)n * 4);
    unsigned* bucketPtr = (unsigned*)carve((NBUCK + 1) * 4);
    unsigned* bucketTot = (unsigned*)carve(NBUCK * 4);
    unsigned* cnt       = (unsigned*)carve((size_t)NBUCK * NB * 4);   // 1 MB
    unsigned* p0        = (unsigned*)carve(((size_t)n + 1) * 4);
    h16*      bufA      = (h16*)carve((size_t)n * F_HID * 2);         // 3.2 MB fp16
    h16*      bufB      = (h16*)carve((size_t)n * F_HID * 2);         // 3.2 MB fp16
    // binned (E words = 25.6 MB) and col (E words) live in d_out (55.2 MB);
    // both fully consumed before k_out overwrites d_out.
    unsigned* binned = (unsigned*)d_out;
    int*      col    = (int*)d_out + (size_t)E;

    const int B = 256;
    const int nbAgg8 = (n * 8 + B - 1) / B;   // 3125
    k_bincount<<<NB, 1024, 0, stream>>>(idx, cnt, E);
    k_scanA   <<<NBUCK, B, 0, stream>>>(cnt, bucketTot);
    k_scanB   <<<1, NBUCK, 0, stream>>>(bucketTot, bucketPtr);
    k_binfill <<<NB, 1024, 0, stream>>>(idx, cnt, bucketPtr, binned, E);
    k_ptrfill <<<NBUCK, 1024, 0, stream>>>(bucketPtr, binned, p0, dinv, col, n, E);
    k_gemm1   <<<(n + 15) / 16, B, 0, stream>>>(x, W1, dinv, bufA, n);
    // layer 1 (edge-split pass, fused relu epilogue)
    k_agg<1>  <<<nbAgg8, B, 0, stream>>>(p0, col, (const h16x8*)bufA,
                                         (h16x8*)bufB, dinv, b1, n);
    // layer 2
    k_agg<0>  <<<nbAgg8, B, 0, stream>>>(p0, col, (const h16x8*)bufB,
                                         (h16x8*)bufA, dinv, b1, n);
    k_out     <<<(n + OUT_NV - 1) / OUT_NV, B, 0, stream>>>(bufA, W2, b2, out, n);
}

// Round 19
// 238.083 us; speedup vs baseline: 1.0011x; 1.0011x over previous
//
#include <hip/hip_runtime.h>
#include <cstdint>

#define F_IN  128
#define F_HID 16
#define F_OUT 138
#define NBUCK 512        // dst buckets
#define NPB_SHIFT 8
#define NPB 256          // nodes per bucket
#define NB  512          // edge slabs for binning passes
#define SLAB_CAP 12544   // >= ceil(E/NB) = 12500
#define STAGE_CAP 18432  // >= max bucket edges (~16.4k avg + slack)
#define OUT_NV 16        // nodes per k_out block

typedef float f32x8 __attribute__((ext_vector_type(8)));
typedef int   i32x4 __attribute__((ext_vector_type(4)));
typedef _Float16 h16;
typedef _Float16 h16x8 __attribute__((ext_vector_type(8)));   // 16 B

// ---------------------------------------------------------------------------
// Inline edge_index dtype detection: int64 (LE, values < 2^31) -> every odd
// int32 word is zero. Returns 2 (int64 stride in words) or 1 (int32).
__device__ __forceinline__ int edge_mult(const int* __restrict__ idx) {
    int nz = 0;
#pragma unroll
    for (int i = 1; i < 64; i += 2) nz |= idx[i];
    return nz ? 1 : 2;
}

// Pass A: per-slab LDS histogram of dst-buckets (reads dst only).
__global__ void __launch_bounds__(1024, 8)
k_bincount(const int* __restrict__ idx, unsigned* __restrict__ cnt, int E) {
    __shared__ unsigned hist[NBUCK];
    int tid = threadIdx.x;
    if (tid < NBUCK) hist[tid] = 0;
    __syncthreads();
    const int mult = edge_mult(idx);
    int slab = (E + NB - 1) / NB;
    int start = blockIdx.x * slab, end = min(E, start + slab);
    if (mult == 2) {
        for (int e = start + tid; e < end; e += 1024)
            atomicAdd(&hist[((const int2*)idx)[(size_t)E + e].x >> NPB_SHIFT], 1u);
    } else {
        for (int e = start + tid; e < end; e += 1024)
            atomicAdd(&hist[idx[(size_t)E + e] >> NPB_SHIFT], 1u);
    }
    __syncthreads();
    if (tid < NBUCK) cnt[(size_t)tid * NB + blockIdx.x] = hist[tid];
}

// Scan step 1: one block per bucket; exclusive-scan its NB slab counts in
// place (pair-per-thread Hillis-Steele); emit bucket total.
__global__ void k_scanA(unsigned* __restrict__ cnt, unsigned* __restrict__ bucketTot) {
    __shared__ unsigned sh[256];
    int t = threadIdx.x;
    unsigned* row = cnt + (size_t)blockIdx.x * NB;
    unsigned e0 = row[2 * t], e1 = row[2 * t + 1];
    unsigned pair = e0 + e1;
    sh[t] = pair;
    __syncthreads();
    for (int off = 1; off < 256; off <<= 1) {
        unsigned v = (t >= off) ? sh[t - off] : 0u;
        __syncthreads();
        sh[t] += v;
        __syncthreads();
    }
    unsigned excl = sh[t] - pair;
    row[2 * t] = excl;
    row[2 * t + 1] = excl + e0;
    if (t == 255) bucketTot[blockIdx.x] = sh[255];
}

// Scan step 2: one block (512 threads); exclusive scan of bucket totals.
__global__ void k_scanB(const unsigned* __restrict__ bucketTot,
                        unsigned* __restrict__ bucketPtr) {
    __shared__ unsigned sh[NBUCK];
    int t = threadIdx.x;
    unsigned c = bucketTot[t];
    sh[t] = c;
    __syncthreads();
    for (int off = 1; off < NBUCK; off <<= 1) {
        unsigned v = (t >= off) ? sh[t - off] : 0u;
        __syncthreads();
        sh[t] += v;
        __syncthreads();
    }
    bucketPtr[t] = sh[t] - c;          // exclusive
    if (t == NBUCK - 1) bucketPtr[NBUCK] = sh[t];
}

// Pass B with LDS write-combining, 1024 threads: histogram slab by bucket,
// scan, scatter the slab's edges into LDS staging sorted by bucket, then
// 16-lane-group copy-out to each (slab,bucket) global segment (~24 entries).
// Packed entry: (dstLocal<<17) | src  (8+17 = 25 bits, src < 2^17).
__global__ void __launch_bounds__(1024, 8)
k_binfill(const int* __restrict__ idx,
          const unsigned* __restrict__ cnt,
          const unsigned* __restrict__ bucketPtr,
          unsigned* __restrict__ binned, int E) {
    __shared__ unsigned hist[NBUCK];
    __shared__ unsigned sofs[NBUCK];
    __shared__ unsigned scur[NBUCK];
    __shared__ unsigned stage[SLAB_CAP];   // 50 KB
    int tid = threadIdx.x;
    if (tid < NBUCK) hist[tid] = 0;
    __syncthreads();
    const int mult = edge_mult(idx);
    int slab = (E + NB - 1) / NB;
    int start = blockIdx.x * slab, end = min(E, start + slab);
    // phase 1: histogram (dst only)
    if (mult == 2) {
        for (int e = start + tid; e < end; e += 1024)
            atomicAdd(&hist[((const int2*)idx)[(size_t)E + e].x >> NPB_SHIFT], 1u);
    } else {
        for (int e = start + tid; e < end; e += 1024)
            atomicAdd(&hist[idx[(size_t)E + e] >> NPB_SHIFT], 1u);
    }
    __syncthreads();
    // phase 2: exclusive scan of NBUCK counts (Hillis-Steele on tid<NBUCK)
    if (tid < NBUCK) scur[tid] = hist[tid];
    __syncthreads();
    for (int off = 1; off < NBUCK; off <<= 1) {
        unsigned v = 0;
        if (tid < NBUCK && tid >= off) v = scur[tid - off];
        __syncthreads();
        if (tid < NBUCK) scur[tid] += v;
        __syncthreads();
    }
    if (tid < NBUCK) {
        unsigned ex = scur[tid] - hist[tid];
        sofs[tid] = ex;
        scur[tid] = ex;
    }
    __syncthreads();
    // phase 3: scatter slab edges into LDS staging sorted by bucket
    for (int e = start + tid; e < end; e += 1024) {
        int s, d;
        if (mult == 2) { s = ((const int2*)idx)[e].x; d = ((const int2*)idx)[(size_t)E + e].x; }
        else           { s = idx[e];                  d = idx[(size_t)E + e]; }
        unsigned pos = atomicAdd(&scur[d >> NPB_SHIFT], 1u);
        stage[pos] = ((unsigned)(d & (NPB - 1)) << 17) | (unsigned)s;
    }
    __syncthreads();
    // phase 4: copy-out, one 16-lane group per bucket segment
    int g = tid >> 4, lane = tid & 15;       // 64 groups
    for (int b = g; b < NBUCK; b += 64) {
        unsigned s0 = sofs[b], len = scur[b] - s0;
        if (len == 0) continue;
        unsigned gbase = cnt[(size_t)b * NB + blockIdx.x] + bucketPtr[b];
        for (unsigned i = lane; i < len; i += 16)
            binned[gbase + i] = stage[s0 + i];
    }
}

// Fused per-bucket (1024 threads): degree histogram -> scan -> ptr + dinv,
// then sort the bucket's edges into LDS staging by node and stream out
// col[] as one coalesced sequential copy (fallback: direct scatter).
__global__ void __launch_bounds__(1024, 8)
k_ptrfill(const unsigned* __restrict__ bucketPtr,
          const unsigned* __restrict__ binned,
          unsigned* __restrict__ p0,
          float* __restrict__ dinv, int* __restrict__ col,
          int n, int E) {
    __shared__ unsigned deg[NPB];
    __shared__ unsigned cur[NPB];
    __shared__ unsigned sh[NPB];
    __shared__ unsigned stage[STAGE_CAP];   // 72 KB
    int tid = threadIdx.x, bb = blockIdx.x;
    if (tid < NPB) deg[tid] = 0;
    __syncthreads();
    unsigned start = bucketPtr[bb], end = bucketPtr[bb + 1];
    unsigned cntE = end - start;
    for (unsigned i = start + tid; i < end; i += 1024)
        atomicAdd(&deg[binned[i] >> 17], 1u);
    __syncthreads();
    unsigned d0 = 0;
    if (tid < NPB) { d0 = deg[tid]; sh[tid] = d0; }
    __syncthreads();
    for (int off = 1; off < NPB; off <<= 1) {
        unsigned v = 0;
        if (tid < NPB && tid >= off) v = sh[tid - off];
        __syncthreads();
        if (tid < NPB) sh[tid] += v;
        __syncthreads();
    }
    if (tid < NPB) {
        unsigned lbase = sh[tid] - d0;        // exclusive prefix (local)
        cur[tid] = lbase;
        int v = (bb << NPB_SHIFT) + tid;
        if (v < n) {
            p0[v] = start + lbase;
            dinv[v] = rsqrtf((float)(d0 + 1u));   // +1 self-loop
        }
    }
    if (bb == 0 && tid == 0) p0[n] = (unsigned)E;
    __syncthreads();
    if (cntE <= STAGE_CAP) {
        for (unsigned i = start + tid; i < end; i += 1024) {
            unsigned entry = binned[i];
            unsigned pos = atomicAdd(&cur[entry >> 17], 1u);
            stage[pos] = entry & 0x1FFFFu;
        }
        __syncthreads();
        for (unsigned i = tid; i < cntE; i += 1024)
            col[start + i] = (int)stage[i];
    } else {
        for (unsigned i = start + tid; i < end; i += 1024) {
            unsigned entry = binned[i];
            unsigned pos = atomicAdd(&cur[entry >> 17], 1u);
            col[start + pos] = (int)(entry & 0x1FFFFu);
        }
    }
}

// g1[v][j] = dinv[v] * (x[v] . W1[:,j]), stored as fp16 (gather table is
// then 3.2 MB -> fits one XCD's 4 MB L2). 16 nodes x 16 feats per block.
__global__ void k_gemm1(const float* __restrict__ x, const float* __restrict__ W1,
                        const float* __restrict__ dinv,
                        h16* __restrict__ g1, int n) {
    __shared__ float w1s[F_IN * F_HID];     // 8 KB
    __shared__ float xs[16][F_IN + 4];
    int tid = threadIdx.x;
    for (int i = tid; i < F_IN * F_HID; i += 256) w1s[i] = W1[i];
    int nb = blockIdx.x * 16;
    for (int q = tid; q < 512; q += 256) {
        int r = q >> 5, k4 = q & 31;
        int g = nb + r;
        float4 v = make_float4(0.f, 0.f, 0.f, 0.f);
        if (g < n) v = ((const float4*)x)[(size_t)g * 32 + k4];
        xs[r][k4 * 4 + 0] = v.x; xs[r][k4 * 4 + 1] = v.y;
        xs[r][k4 * 4 + 2] = v.z; xs[r][k4 * 4 + 3] = v.w;
    }
    __syncthreads();
    int r = tid >> 4, j = tid & 15;
    int g = nb + r;
    if (g < n) {
        float acc = 0.f;
#pragma unroll
        for (int k = 0; k < F_IN; ++k) acc += xs[r][k] * w1s[k * F_HID + j];
        g1[(size_t)g * F_HID + j] = (h16)(acc * dinv[g]);
    }
}

// Pull-mode CSR aggregation, 8 threads/node: (sub=0..3) x (q=0..1).
// Transaction-optimized inner loop (8 edges/iter per lane pair):
//  - lane pair cooperatively loads 8 edge indices as two adjacent int4
//    (1 transaction/pair), exchanging halves via __shfl_xor(.,1)
//  - each lane gathers its q-half of every edge's 32 B row, in matched
//    order across the pair -> the coalescer merges the two halves into
//    ONE transaction per edge (round-17 behavior).
// => ~1.125 scattered transactions/edge (was 2.0 in r17, 2.25 in r18).
// Partials combined via __shfl_xor masks 2,4; sub==0 adds self-loop,
// applies epilogue, stores fp16.
template <int RELU>
__global__ void __launch_bounds__(256)
k_agg(const unsigned* __restrict__ p0, const int* __restrict__ col,
      const h16x8* __restrict__ gin8, h16x8* __restrict__ gout8,
      const float* __restrict__ dinv, const float* __restrict__ b1, int n) {
    int t = blockIdx.x * blockDim.x + threadIdx.x;
    int v = t >> 3;
    int sub = (t >> 1) & 3;
    int q = t & 1;
    if (v >= n) return;
    unsigned rs = p0[v], re = p0[v + 1];
    unsigned deg = re - rs;
    unsigned chunk = (deg + 3) >> 2;
    unsigned cs = rs + sub * chunk;
    unsigned ce = min(re, cs + chunk);
    if (cs > re) cs = re;
    f32x8 acc = (f32x8)0.f;
    unsigned i = cs;
    // scalar head until col+i is 16B-aligned (both lanes of the pair agree)
    for (; i < ce && (i & 3u); ++i)
        acc += __builtin_convertvector(
            gin8[(size_t)__builtin_nontemporal_load(col + i) * 2 + q], f32x8);
    // vector body: 8 edges per iteration, pair-cooperative col load
    for (; i + 8 <= ce; i += 8) {
        i32x4 um = __builtin_nontemporal_load((const i32x4*)(col + i + 4 * q));
        int pa = __shfl_xor(um[0], 1);
        int pb = __shfl_xor(um[1], 1);
        int pc = __shfl_xor(um[2], 1);
        int pd = __shfl_xor(um[3], 1);
        // edge order e0..e7 identical on both lanes (halves coalesce per edge)
        int e0 = q ? pa : um[0];
        int e1 = q ? pb : um[1];
        int e2 = q ? pc : um[2];
        int e3 = q ? pd : um[3];
        int e4 = q ? um[0] : pa;
        int e5 = q ? um[1] : pb;
        int e6 = q ? um[2] : pc;
        int e7 = q ? um[3] : pd;
        h16x8 a0 = gin8[(size_t)e0 * 2 + q];
        h16x8 a1 = gin8[(size_t)e1 * 2 + q];
        h16x8 a2 = gin8[(size_t)e2 * 2 + q];
        h16x8 a3 = gin8[(size_t)e3 * 2 + q];
        h16x8 a4 = gin8[(size_t)e4 * 2 + q];
        h16x8 a5 = gin8[(size_t)e5 * 2 + q];
        h16x8 a6 = gin8[(size_t)e6 * 2 + q];
        h16x8 a7 = gin8[(size_t)e7 * 2 + q];
        f32x8 s01 = __builtin_convertvector(a0, f32x8) + __builtin_convertvector(a1, f32x8);
        f32x8 s23 = __builtin_convertvector(a2, f32x8) + __builtin_convertvector(a3, f32x8);
        f32x8 s45 = __builtin_convertvector(a4, f32x8) + __builtin_convertvector(a5, f32x8);
        f32x8 s67 = __builtin_convertvector(a6, f32x8) + __builtin_convertvector(a7, f32x8);
        acc += (s01 + s23) + (s45 + s67);
    }
    // scalar tail
    for (; i < ce; ++i)
        acc += __builtin_convertvector(
            gin8[(size_t)__builtin_nontemporal_load(col + i) * 2 + q], f32x8);
    // combine the 4 sub-partials (lane bits 1,2 within the 8-lane node group)
#pragma unroll
    for (int k = 0; k < 8; ++k) acc[k] += __shfl_xor((float)acc[k], 2);
#pragma unroll
    for (int k = 0; k < 8; ++k) acc[k] += __shfl_xor((float)acc[k], 4);
    if (sub == 0) {
        size_t o = (size_t)v * 2 + q;
        acc += __builtin_convertvector(gin8[o], f32x8);   // self-loop
        float di = dinv[v];
        f32x8 r;
        if (RELU) {
            const float* b = b1 + q * 8;
#pragma unroll
            for (int k = 0; k < 8; ++k) r[k] = fmaxf(di * acc[k] + b[k], 0.f) * di;
        } else {
            r = acc * di;
        }
        gout8[o] = __builtin_convertvector(r, h16x8);   // cached: next pass reads it
    }
}

// Node-tiled output GEMM: block owns OUT_NV contiguous nodes; fp16 B rows
// staged once in LDS as fp32, outputs written coalesced NT.
// out[v][c] = B[v] . W2[:,c] + b2[c]   (dinv already folded into B)
__global__ void __launch_bounds__(256)
k_out(const h16* __restrict__ B,
      const float* __restrict__ W2, const float* __restrict__ b2,
      float* __restrict__ out, int n) {
    __shared__ float w2s[F_HID * F_OUT];   // 8.8 KB
    __shared__ float b2s[F_OUT];
    __shared__ float Bs[OUT_NV][F_HID];    // 1 KB
    int tid = threadIdx.x;
    for (int i = tid; i < F_HID * F_OUT; i += 256) w2s[i] = W2[i];
    if (tid < F_OUT) b2s[tid] = b2[tid];
    int vbase = blockIdx.x * OUT_NV;
    {
        int vl = tid >> 4, j = tid & 15;
        int v = vbase + vl;
        Bs[vl][j] = (v < n) ? (float)B[(size_t)v * F_HID + j] : 0.f;
    }
    __syncthreads();
    const int total = OUT_NV * F_OUT;   // 2208
    for (int q = tid; q < total; q += 256) {
        int vl = q / F_OUT, c = q - vl * F_OUT;
        int v = vbase + vl;
        if (v >= n) continue;
        float acc = b2s[c];
#pragma unroll
        for (int j = 0; j < F_HID; ++j) acc += Bs[vl][j] * w2s[j * F_OUT + c];
        __builtin_nontemporal_store(acc, out + (size_t)v * F_OUT + c);
    }
}

extern "C" void kernel_launch(void* const* d_in, const int* in_sizes, int n_in,
                              void* d_out, int out_size, void* d_ws, size_t ws_size,
                              hipStream_t stream) {
    const float* x   = (const float*)d_in[0];
    const int*   idx = (const int*)d_in[1];
    const float* W1  = (const float*)d_in[2];
    const float* b1  = (const float*)d_in[3];
    const float* W2  = (const float*)d_in[4];
    const float* b2  = (const float*)d_in[5];
    float* out = (float*)d_out;

    const int n = in_sizes[0] / F_IN;       // 100000
    const int E = in_sizes[1] / 2;          // 6400000

    char* ws = (char*)d_ws;
    size_t off = 0;
    auto carve = [&](size_t bytes) { char* p = ws + off; off += (bytes + 255) / 256 * 256; return p; };
    float*    dinv      = (float*)carve((size_t)n * 4);
    unsigned* bucketPtr = (unsigned*)carve((NBUCK + 1) * 4);
    unsigned* bucketTot = (unsigned*)carve(NBUCK * 4);
    unsigned* cnt       = (unsigned*)carve((size_t)NBUCK * NB * 4);   // 1 MB
    unsigned* p0        = (unsigned*)carve(((size_t)n + 1) * 4);
    h16*      bufA      = (h16*)carve((size_t)n * F_HID * 2);         // 3.2 MB fp16
    h16*      bufB      = (h16*)carve((size_t)n * F_HID * 2);         // 3.2 MB fp16
    // binned (E words = 25.6 MB) and col (E words) live in d_out (55.2 MB);
    // both fully consumed before k_out overwrites d_out.
    unsigned* binned = (unsigned*)d_out;
    int*      col    = (int*)d_out + (size_t)E;

    const int B = 256;
    const int nbAgg8 = (n * 8 + B - 1) / B;   // 3125
    k_bincount<<<NB, 1024, 0, stream>>>(idx, cnt, E);
    k_scanA   <<<NBUCK, B, 0, stream>>>(cnt, bucketTot);
    k_scanB   <<<1, NBUCK, 0, stream>>>(bucketTot, bucketPtr);
    k_binfill <<<NB, 1024, 0, stream>>>(idx, cnt, bucketPtr, binned, E);
    k_ptrfill <<<NBUCK, 1024, 0, stream>>>(bucketPtr, binned, p0, dinv, col, n, E);
    k_gemm1   <<<(n + 15) / 16, B, 0, stream>>>(x, W1, dinv, bufA, n);
    // layer 1 (edge-split pass, fused relu epilogue)
    k_agg<1>  <<<nbAgg8, B, 0, stream>>>(p0, col, (const h16x8*)bufA,
                                         (h16x8*)bufB, dinv, b1, n);
    // layer 2
    k_agg<0>  <<<nbAgg8, B, 0, stream>>>(p0, col, (const h16x8*)bufB,
                                         (h16x8*)bufA, dinv, b1, n);
    k_out     <<<(n + OUT_NV - 1) / OUT_NV, B, 0, stream>>>(bufA, W2, b2, out, n);
}

// Round 20
// 229.628 us; speedup vs baseline: 1.0379x; 1.0368x over previous
//
#include <hip/hip_runtime.h>
#include <cstdint>

#define F_IN  128
#define F_HID 16
#define F_OUT 138
#define NBUCK 512        // dst buckets
#define NPB_SHIFT 8
#define NPB 256          // nodes per bucket
#define NB  512          // edge slabs for binning passes
#define SLAB_CAP 12544   // >= ceil(E/NB) = 12500
#define STAGE_CAP 18432  // >= max bucket edges (~16.4k avg + slack)
#define OUT_NV 16        // nodes per k_out block
#define AGG_BLOCKS 2048  // 8 blocks/CU exactly (persistent agg)

typedef float f32x8 __attribute__((ext_vector_type(8)));
typedef _Float16 h16;
typedef _Float16 h16x8 __attribute__((ext_vector_type(8)));   // 16 B

// ---------------------------------------------------------------------------
// Inline edge_index dtype detection: int64 (LE, values < 2^31) -> every odd
// int32 word is zero. Returns 2 (int64 stride in words) or 1 (int32).
__device__ __forceinline__ int edge_mult(const int* __restrict__ idx) {
    int nz = 0;
#pragma unroll
    for (int i = 1; i < 64; i += 2) nz |= idx[i];
    return nz ? 1 : 2;
}

// Pass A: per-slab LDS histogram of dst-buckets (reads dst only).
__global__ void __launch_bounds__(1024, 8)
k_bincount(const int* __restrict__ idx, unsigned* __restrict__ cnt, int E) {
    __shared__ unsigned hist[NBUCK];
    int tid = threadIdx.x;
    if (tid < NBUCK) hist[tid] = 0;
    __syncthreads();
    const int mult = edge_mult(idx);
    int slab = (E + NB - 1) / NB;
    int start = blockIdx.x * slab, end = min(E, start + slab);
    if (mult == 2) {
        for (int e = start + tid; e < end; e += 1024)
            atomicAdd(&hist[((const int2*)idx)[(size_t)E + e].x >> NPB_SHIFT], 1u);
    } else {
        for (int e = start + tid; e < end; e += 1024)
            atomicAdd(&hist[idx[(size_t)E + e] >> NPB_SHIFT], 1u);
    }
    __syncthreads();
    if (tid < NBUCK) cnt[(size_t)tid * NB + blockIdx.x] = hist[tid];
}

// Scan step 1: one block per bucket; exclusive-scan its NB slab counts in
// place (pair-per-thread Hillis-Steele); emit bucket total.
__global__ void k_scanA(unsigned* __restrict__ cnt, unsigned* __restrict__ bucketTot) {
    __shared__ unsigned sh[256];
    int t = threadIdx.x;
    unsigned* row = cnt + (size_t)blockIdx.x * NB;
    unsigned e0 = row[2 * t], e1 = row[2 * t + 1];
    unsigned pair = e0 + e1;
    sh[t] = pair;
    __syncthreads();
    for (int off = 1; off < 256; off <<= 1) {
        unsigned v = (t >= off) ? sh[t - off] : 0u;
        __syncthreads();
        sh[t] += v;
        __syncthreads();
    }
    unsigned excl = sh[t] - pair;
    row[2 * t] = excl;
    row[2 * t + 1] = excl + e0;
    if (t == 255) bucketTot[blockIdx.x] = sh[255];
}

// Scan step 2: one block (512 threads); exclusive scan of bucket totals.
__global__ void k_scanB(const unsigned* __restrict__ bucketTot,
                        unsigned* __restrict__ bucketPtr) {
    __shared__ unsigned sh[NBUCK];
    int t = threadIdx.x;
    unsigned c = bucketTot[t];
    sh[t] = c;
    __syncthreads();
    for (int off = 1; off < NBUCK; off <<= 1) {
        unsigned v = (t >= off) ? sh[t - off] : 0u;
        __syncthreads();
        sh[t] += v;
        __syncthreads();
    }
    bucketPtr[t] = sh[t] - c;          // exclusive
    if (t == NBUCK - 1) bucketPtr[NBUCK] = sh[t];
}

// Pass B with LDS write-combining, 1024 threads: histogram slab by bucket,
// scan, scatter the slab's edges into LDS staging sorted by bucket, then
// 16-lane-group copy-out to each (slab,bucket) global segment (~24 entries).
// Packed entry: (dstLocal<<17) | src  (8+17 = 25 bits, src < 2^17).
__global__ void __launch_bounds__(1024, 8)
k_binfill(const int* __restrict__ idx,
          const unsigned* __restrict__ cnt,
          const unsigned* __restrict__ bucketPtr,
          unsigned* __restrict__ binned, int E) {
    __shared__ unsigned hist[NBUCK];
    __shared__ unsigned sofs[NBUCK];
    __shared__ unsigned scur[NBUCK];
    __shared__ unsigned stage[SLAB_CAP];   // 50 KB
    int tid = threadIdx.x;
    if (tid < NBUCK) hist[tid] = 0;
    __syncthreads();
    const int mult = edge_mult(idx);
    int slab = (E + NB - 1) / NB;
    int start = blockIdx.x * slab, end = min(E, start + slab);
    // phase 1: histogram (dst only)
    if (mult == 2) {
        for (int e = start + tid; e < end; e += 1024)
            atomicAdd(&hist[((const int2*)idx)[(size_t)E + e].x >> NPB_SHIFT], 1u);
    } else {
        for (int e = start + tid; e < end; e += 1024)
            atomicAdd(&hist[idx[(size_t)E + e] >> NPB_SHIFT], 1u);
    }
    __syncthreads();
    // phase 2: exclusive scan of NBUCK counts (Hillis-Steele on tid<NBUCK)
    if (tid < NBUCK) scur[tid] = hist[tid];
    __syncthreads();
    for (int off = 1; off < NBUCK; off <<= 1) {
        unsigned v = 0;
        if (tid < NBUCK && tid >= off) v = scur[tid - off];
        __syncthreads();
        if (tid < NBUCK) scur[tid] += v;
        __syncthreads();
    }
    if (tid < NBUCK) {
        unsigned ex = scur[tid] - hist[tid];
        sofs[tid] = ex;
        scur[tid] = ex;
    }
    __syncthreads();
    // phase 3: scatter slab edges into LDS staging sorted by bucket
    for (int e = start + tid; e < end; e += 1024) {
        int s, d;
        if (mult == 2) { s = ((const int2*)idx)[e].x; d = ((const int2*)idx)[(size_t)E + e].x; }
        else           { s = idx[e];                  d = idx[(size_t)E + e]; }
        unsigned pos = atomicAdd(&scur[d >> NPB_SHIFT], 1u);
        stage[pos] = ((unsigned)(d & (NPB - 1)) << 17) | (unsigned)s;
    }
    __syncthreads();
    // phase 4: copy-out, one 16-lane group per bucket segment
    int g = tid >> 4, lane = tid & 15;       // 64 groups
    for (int b = g; b < NBUCK; b += 64) {
        unsigned s0 = sofs[b], len = scur[b] - s0;
        if (len == 0) continue;
        unsigned gbase = cnt[(size_t)b * NB + blockIdx.x] + bucketPtr[b];
        for (unsigned i = lane; i < len; i += 16)
            binned[gbase + i] = stage[s0 + i];
    }
}

// Fused per-bucket (1024 threads): degree histogram -> scan -> ptr + dinv,
// then sort the bucket's edges into LDS staging by node and stream out
// col[] as one coalesced sequential copy (fallback: direct scatter).
__global__ void __launch_bounds__(1024, 8)
k_ptrfill(const unsigned* __restrict__ bucketPtr,
          const unsigned* __restrict__ binned,
          unsigned* __restrict__ p0,
          float* __restrict__ dinv, int* __restrict__ col,
          int n, int E) {
    __shared__ unsigned deg[NPB];
    __shared__ unsigned cur[NPB];
    __shared__ unsigned sh[NPB];
    __shared__ unsigned stage[STAGE_CAP];   // 72 KB
    int tid = threadIdx.x, bb = blockIdx.x;
    if (tid < NPB) deg[tid] = 0;
    __syncthreads();
    unsigned start = bucketPtr[bb], end = bucketPtr[bb + 1];
    unsigned cntE = end - start;
    for (unsigned i = start + tid; i < end; i += 1024)
        atomicAdd(&deg[binned[i] >> 17], 1u);
    __syncthreads();
    unsigned d0 = 0;
    if (tid < NPB) { d0 = deg[tid]; sh[tid] = d0; }
    __syncthreads();
    for (int off = 1; off < NPB; off <<= 1) {
        unsigned v = 0;
        if (tid < NPB && tid >= off) v = sh[tid - off];
        __syncthreads();
        if (tid < NPB) sh[tid] += v;
        __syncthreads();
    }
    if (tid < NPB) {
        unsigned lbase = sh[tid] - d0;        // exclusive prefix (local)
        cur[tid] = lbase;
        int v = (bb << NPB_SHIFT) + tid;
        if (v < n) {
            p0[v] = start + lbase;
            dinv[v] = rsqrtf((float)(d0 + 1u));   // +1 self-loop
        }
    }
    if (bb == 0 && tid == 0) p0[n] = (unsigned)E;
    __syncthreads();
    if (cntE <= STAGE_CAP) {
        for (unsigned i = start + tid; i < end; i += 1024) {
            unsigned entry = binned[i];
            unsigned pos = atomicAdd(&cur[entry >> 17], 1u);
            stage[pos] = entry & 0x1FFFFu;
        }
        __syncthreads();
        for (unsigned i = tid; i < cntE; i += 1024)
            col[start + i] = (int)stage[i];
    } else {
        for (unsigned i = start + tid; i < end; i += 1024) {
            unsigned entry = binned[i];
            unsigned pos = atomicAdd(&cur[entry >> 17], 1u);
            col[start + pos] = (int)(entry & 0x1FFFFu);
        }
    }
}

// g1[v][j] = dinv[v] * (x[v] . W1[:,j]), stored as fp16 (gather table is
// then 3.2 MB -> fits one XCD's 4 MB L2). 16 nodes x 16 feats per block.
__global__ void k_gemm1(const float* __restrict__ x, const float* __restrict__ W1,
                        const float* __restrict__ dinv,
                        h16* __restrict__ g1, int n) {
    __shared__ float w1s[F_IN * F_HID];     // 8 KB
    __shared__ float xs[16][F_IN + 4];
    int tid = threadIdx.x;
    for (int i = tid; i < F_IN * F_HID; i += 256) w1s[i] = W1[i];
    int nb = blockIdx.x * 16;
    for (int q = tid; q < 512; q += 256) {
        int r = q >> 5, k4 = q & 31;
        int g = nb + r;
        float4 v = make_float4(0.f, 0.f, 0.f, 0.f);
        if (g < n) v = ((const float4*)x)[(size_t)g * 32 + k4];
        xs[r][k4 * 4 + 0] = v.x; xs[r][k4 * 4 + 1] = v.y;
        xs[r][k4 * 4 + 2] = v.z; xs[r][k4 * 4 + 3] = v.w;
    }
    __syncthreads();
    int r = tid >> 4, j = tid & 15;
    int g = nb + r;
    if (g < n) {
        float acc = 0.f;
#pragma unroll
        for (int k = 0; k < F_IN; ++k) acc += xs[r][k] * w1s[k * F_HID + j];
        g1[(size_t)g * F_HID + j] = (h16)(acc * dinv[g]);
    }
}

// Pull-mode CSR aggregation, PERSISTENT grid-stride version of the r17-best
// inner loop. 8 threads/node: (sub=0..3) x (q=0..1); each thread gathers a
// contiguous quarter of the node's edges (h16x8 16 B loads, the lane pair's
// two halves coalesce to ONE transaction/edge), fp32 accumulate, combine
// via __shfl_xor masks 2,4. 2048 blocks (8/CU) loop over node slots ->
// sustained full residency (the r17 grid was 1.5 short dispatch rounds,
// occupancy 42%).
template <int RELU>
__global__ void __launch_bounds__(256, 8)
k_agg(const unsigned* __restrict__ p0, const int* __restrict__ col,
      const h16x8* __restrict__ gin8, h16x8* __restrict__ gout8,
      const float* __restrict__ dinv, const float* __restrict__ b1, int n) {
    int t = blockIdx.x * blockDim.x + threadIdx.x;
    int sub = (t >> 1) & 3;
    int q = t & 1;
    const int slots = (gridDim.x * blockDim.x) >> 3;   // node slots per round
    for (int v = t >> 3; v < n; v += slots) {
        unsigned rs = p0[v], re = p0[v + 1];
        unsigned deg = re - rs;
        unsigned chunk = (deg + 3) >> 2;
        unsigned cs = rs + sub * chunk;
        unsigned ce = min(re, cs + chunk);
        if (cs > re) cs = re;
        f32x8 acc = (f32x8)0.f;
        unsigned i = cs;
        for (; i + 8 <= ce; i += 8) {
            int u0 = __builtin_nontemporal_load(col + i);
            int u1 = __builtin_nontemporal_load(col + i + 1);
            int u2 = __builtin_nontemporal_load(col + i + 2);
            int u3 = __builtin_nontemporal_load(col + i + 3);
            int u4 = __builtin_nontemporal_load(col + i + 4);
            int u5 = __builtin_nontemporal_load(col + i + 5);
            int u6 = __builtin_nontemporal_load(col + i + 6);
            int u7 = __builtin_nontemporal_load(col + i + 7);
            h16x8 a0 = gin8[(size_t)u0 * 2 + q];
            h16x8 a1 = gin8[(size_t)u1 * 2 + q];
            h16x8 a2 = gin8[(size_t)u2 * 2 + q];
            h16x8 a3 = gin8[(size_t)u3 * 2 + q];
            h16x8 a4 = gin8[(size_t)u4 * 2 + q];
            h16x8 a5 = gin8[(size_t)u5 * 2 + q];
            h16x8 a6 = gin8[(size_t)u6 * 2 + q];
            h16x8 a7 = gin8[(size_t)u7 * 2 + q];
            f32x8 s01 = __builtin_convertvector(a0, f32x8) + __builtin_convertvector(a1, f32x8);
            f32x8 s23 = __builtin_convertvector(a2, f32x8) + __builtin_convertvector(a3, f32x8);
            f32x8 s45 = __builtin_convertvector(a4, f32x8) + __builtin_convertvector(a5, f32x8);
            f32x8 s67 = __builtin_convertvector(a6, f32x8) + __builtin_convertvector(a7, f32x8);
            acc += (s01 + s23) + (s45 + s67);
        }
        for (; i < ce; ++i)
            acc += __builtin_convertvector(
                gin8[(size_t)__builtin_nontemporal_load(col + i) * 2 + q], f32x8);
        // combine the 4 sub-partials (lane bits 1,2 within the 8-lane group)
#pragma unroll
        for (int k = 0; k < 8; ++k) acc[k] += __shfl_xor((float)acc[k], 2);
#pragma unroll
        for (int k = 0; k < 8; ++k) acc[k] += __shfl_xor((float)acc[k], 4);
        if (sub == 0) {
            size_t o = (size_t)v * 2 + q;
            acc += __builtin_convertvector(gin8[o], f32x8);   // self-loop
            float di = dinv[v];
            f32x8 r;
            if (RELU) {
                const float* b = b1 + q * 8;
#pragma unroll
                for (int k = 0; k < 8; ++k) r[k] = fmaxf(di * acc[k] + b[k], 0.f) * di;
            } else {
                r = acc * di;
            }
            gout8[o] = __builtin_convertvector(r, h16x8);   // cached: next pass reads it
        }
    }
}

// Node-tiled output GEMM: block owns OUT_NV contiguous nodes; fp16 B rows
// staged once in LDS as fp32, outputs written coalesced NT.
// out[v][c] = B[v] . W2[:,c] + b2[c]   (dinv already folded into B)
__global__ void __launch_bounds__(256)
k_out(const h16* __restrict__ B,
      const float* __restrict__ W2, const float* __restrict__ b2,
      float* __restrict__ out, int n) {
    __shared__ float w2s[F_HID * F_OUT];   // 8.8 KB
    __shared__ float b2s[F_OUT];
    __shared__ float Bs[OUT_NV][F_HID];    // 1 KB
    int tid = threadIdx.x;
    for (int i = tid; i < F_HID * F_OUT; i += 256) w2s[i] = W2[i];
    if (tid < F_OUT) b2s[tid] = b2[tid];
    int vbase = blockIdx.x * OUT_NV;
    {
        int vl = tid >> 4, j = tid & 15;
        int v = vbase + vl;
        Bs[vl][j] = (v < n) ? (float)B[(size_t)v * F_HID + j] : 0.f;
    }
    __syncthreads();
    const int total = OUT_NV * F_OUT;   // 2208
    for (int q = tid; q < total; q += 256) {
        int vl = q / F_OUT, c = q - vl * F_OUT;
        int v = vbase + vl;
        if (v >= n) continue;
        float acc = b2s[c];
#pragma unroll
        for (int j = 0; j < F_HID; ++j) acc += Bs[vl][j] * w2s[j * F_OUT + c];
        __builtin_nontemporal_store(acc, out + (size_t)v * F_OUT + c);
    }
}

extern "C" void kernel_launch(void* const* d_in, const int* in_sizes, int n_in,
                              void* d_out, int out_size, void* d_ws, size_t ws_size,
                              hipStream_t stream) {
    const float* x   = (const float*)d_in[0];
    const int*   idx = (const int*)d_in[1];
    const float* W1  = (const float*)d_in[2];
    const float* b1  = (const float*)d_in[3];
    const float* W2  = (const float*)d_in[4];
    const float* b2  = (const float*)d_in[5];
    float* out = (float*)d_out;

    const int n = in_sizes[0] / F_IN;       // 100000
    const int E = in_sizes[1] / 2;          // 6400000

    char* ws = (char*)d_ws;
    size_t off = 0;
    auto carve = [&](size_t bytes) { char* p = ws + off; off += (bytes + 255) / 256 * 256; return p; };
    float*    dinv      = (float*)carve((size_t)n * 4);
    unsigned* bucketPtr = (unsigned*)carve((NBUCK + 1) * 4);
    unsigned* bucketTot = (unsigned*)carve(NBUCK * 4);
    unsigned* cnt       = (unsigned*)carve((size_t)NBUCK * NB * 4);   // 1 MB
    unsigned* p0        = (unsigned*)carve(((size_t)n + 1) * 4);
    h16*      bufA      = (h16*)carve((size_t)n * F_HID * 2);         // 3.2 MB fp16
    h16*      bufB      = (h16*)carve((size_t)n * F_HID * 2);         // 3.2 MB fp16
    // binned (E words = 25.6 MB) and col (E words) live in d_out (55.2 MB);
    // both fully consumed before k_out overwrites d_out.
    unsigned* binned = (unsigned*)d_out;
    int*      col    = (int*)d_out + (size_t)E;

    const int B = 256;
    k_bincount<<<NB, 1024, 0, stream>>>(idx, cnt, E);
    k_scanA   <<<NBUCK, B, 0, stream>>>(cnt, bucketTot);
    k_scanB   <<<1, NBUCK, 0, stream>>>(bucketTot, bucketPtr);
    k_binfill <<<NB, 1024, 0, stream>>>(idx, cnt, bucketPtr, binned, E);
    k_ptrfill <<<NBUCK, 1024, 0, stream>>>(bucketPtr, binned, p0, dinv, col, n, E);
    k_gemm1   <<<(n + 15) / 16, B, 0, stream>>>(x, W1, dinv, bufA, n);
    // layer 1 (persistent edge-split pass, fused relu epilogue)
    k_agg<1>  <<<AGG_BLOCKS, B, 0, stream>>>(p0, col, (const h16x8*)bufA,
                                             (h16x8*)bufB, dinv, b1, n);
    // layer 2
    k_agg<0>  <<<AGG_BLOCKS, B, 0, stream>>>(p0, col, (const h16x8*)bufB,
                                             (h16x8*)bufA, dinv, b1, n);
    k_out     <<<(n + OUT_NV - 1) / OUT_NV, B, 0, stream>>>(bufA, W2, b2, out, n);
}

// Round 21
// 228.558 us; speedup vs baseline: 1.0428x; 1.0047x over previous
//
#include <hip/hip_runtime.h>
#include <cstdint>

#define F_IN  128
#define F_HID 16
#define F_OUT 138
#define NBUCK 512        // dst buckets
#define NPB_SHIFT 8
#define NPB 256          // nodes per bucket
#define NB  512          // edge slabs for binning passes
#define SLAB_CAP 12544   // >= ceil(E/NB) = 12500
#define STAGE_CAP 18432  // >= max bucket edges (~16.4k avg + slack)
#define OUT_NV 16        // nodes per k_out block
#define AGG_BLOCKS 2048  // 8 blocks/CU exactly (persistent agg)

typedef float f32x8 __attribute__((ext_vector_type(8)));
typedef _Float16 h16;
typedef _Float16 h16x8 __attribute__((ext_vector_type(8)));   // 16 B

// ---------------------------------------------------------------------------
// Inline edge_index dtype detection: int64 (LE, values < 2^31) -> every odd
// int32 word is zero. Returns 2 (int64 stride in words) or 1 (int32).
__device__ __forceinline__ int edge_mult(const int* __restrict__ idx) {
    int nz = 0;
#pragma unroll
    for (int i = 1; i < 64; i += 2) nz |= idx[i];
    return nz ? 1 : 2;
}

// Pass A: per-slab LDS histogram of dst-buckets (reads dst only).
__global__ void __launch_bounds__(1024, 8)
k_bincount(const int* __restrict__ idx, unsigned* __restrict__ cnt, int E) {
    __shared__ unsigned hist[NBUCK];
    int tid = threadIdx.x;
    if (tid < NBUCK) hist[tid] = 0;
    __syncthreads();
    const int mult = edge_mult(idx);
    int slab = (E + NB - 1) / NB;
    int start = blockIdx.x * slab, end = min(E, start + slab);
    if (mult == 2) {
        for (int e = start + tid; e < end; e += 1024)
            atomicAdd(&hist[((const int2*)idx)[(size_t)E + e].x >> NPB_SHIFT], 1u);
    } else {
        for (int e = start + tid; e < end; e += 1024)
            atomicAdd(&hist[idx[(size_t)E + e] >> NPB_SHIFT], 1u);
    }
    __syncthreads();
    if (tid < NBUCK) cnt[(size_t)tid * NB + blockIdx.x] = hist[tid];
}

// Scan step 1: one block per bucket; exclusive-scan its NB slab counts in
// place (pair-per-thread Hillis-Steele); emit bucket total.
__global__ void k_scanA(unsigned* __restrict__ cnt, unsigned* __restrict__ bucketTot) {
    __shared__ unsigned sh[256];
    int t = threadIdx.x;
    unsigned* row = cnt + (size_t)blockIdx.x * NB;
    unsigned e0 = row[2 * t], e1 = row[2 * t + 1];
    unsigned pair = e0 + e1;
    sh[t] = pair;
    __syncthreads();
    for (int off = 1; off < 256; off <<= 1) {
        unsigned v = (t >= off) ? sh[t - off] : 0u;
        __syncthreads();
        sh[t] += v;
        __syncthreads();
    }
    unsigned excl = sh[t] - pair;
    row[2 * t] = excl;
    row[2 * t + 1] = excl + e0;
    if (t == 255) bucketTot[blockIdx.x] = sh[255];
}

// Scan step 2: one block (512 threads); exclusive scan of bucket totals.
__global__ void k_scanB(const unsigned* __restrict__ bucketTot,
                        unsigned* __restrict__ bucketPtr) {
    __shared__ unsigned sh[NBUCK];
    int t = threadIdx.x;
    unsigned c = bucketTot[t];
    sh[t] = c;
    __syncthreads();
    for (int off = 1; off < NBUCK; off <<= 1) {
        unsigned v = (t >= off) ? sh[t - off] : 0u;
        __syncthreads();
        sh[t] += v;
        __syncthreads();
    }
    bucketPtr[t] = sh[t] - c;          // exclusive
    if (t == NBUCK - 1) bucketPtr[NBUCK] = sh[t];
}

// Pass B with LDS write-combining, 1024 threads: histogram slab by bucket,
// scan, scatter the slab's edges into LDS staging sorted by bucket, then
// 16-lane-group copy-out to each (slab,bucket) global segment (~24 entries).
// Packed entry: (dstLocal<<17) | src  (8+17 = 25 bits, src < 2^17).
__global__ void __launch_bounds__(1024, 8)
k_binfill(const int* __restrict__ idx,
          const unsigned* __restrict__ cnt,
          const unsigned* __restrict__ bucketPtr,
          unsigned* __restrict__ binned, int E) {
    __shared__ unsigned hist[NBUCK];
    __shared__ unsigned sofs[NBUCK];
    __shared__ unsigned scur[NBUCK];
    __shared__ unsigned stage[SLAB_CAP];   // 50 KB
    int tid = threadIdx.x;
    if (tid < NBUCK) hist[tid] = 0;
    __syncthreads();
    const int mult = edge_mult(idx);
    int slab = (E + NB - 1) / NB;
    int start = blockIdx.x * slab, end = min(E, start + slab);
    // phase 1: histogram (dst only)
    if (mult == 2) {
        for (int e = start + tid; e < end; e += 1024)
            atomicAdd(&hist[((const int2*)idx)[(size_t)E + e].x >> NPB_SHIFT], 1u);
    } else {
        for (int e = start + tid; e < end; e += 1024)
            atomicAdd(&hist[idx[(size_t)E + e] >> NPB_SHIFT], 1u);
    }
    __syncthreads();
    // phase 2: exclusive scan of NBUCK counts (Hillis-Steele on tid<NBUCK)
    if (tid < NBUCK) scur[tid] = hist[tid];
    __syncthreads();
    for (int off = 1; off < NBUCK; off <<= 1) {
        unsigned v = 0;
        if (tid < NBUCK && tid >= off) v = scur[tid - off];
        __syncthreads();
        if (tid < NBUCK) scur[tid] += v;
        __syncthreads();
    }
    if (tid < NBUCK) {
        unsigned ex = scur[tid] - hist[tid];
        sofs[tid] = ex;
        scur[tid] = ex;
    }
    __syncthreads();
    // phase 3: scatter slab edges into LDS staging sorted by bucket
    for (int e = start + tid; e < end; e += 1024) {
        int s, d;
        if (mult == 2) { s = ((const int2*)idx)[e].x; d = ((const int2*)idx)[(size_t)E + e].x; }
        else           { s = idx[e];                  d = idx[(size_t)E + e]; }
        unsigned pos = atomicAdd(&scur[d >> NPB_SHIFT], 1u);
        stage[pos] = ((unsigned)(d & (NPB - 1)) << 17) | (unsigned)s;
    }
    __syncthreads();
    // phase 4: copy-out, one 16-lane group per bucket segment
    int g = tid >> 4, lane = tid & 15;       // 64 groups
    for (int b = g; b < NBUCK; b += 64) {
        unsigned s0 = sofs[b], len = scur[b] - s0;
        if (len == 0) continue;
        unsigned gbase = cnt[(size_t)b * NB + blockIdx.x] + bucketPtr[b];
        for (unsigned i = lane; i < len; i += 16)
            binned[gbase + i] = stage[s0 + i];
    }
}

// Fused per-bucket (1024 threads): degree histogram -> scan -> ptr + dinv,
// then sort the bucket's edges into LDS staging by node and stream out
// col[] as one coalesced sequential copy (fallback: direct scatter).
__global__ void __launch_bounds__(1024, 8)
k_ptrfill(const unsigned* __restrict__ bucketPtr,
          const unsigned* __restrict__ binned,
          unsigned* __restrict__ p0,
          float* __restrict__ dinv, int* __restrict__ col,
          int n, int E) {
    __shared__ unsigned deg[NPB];
    __shared__ unsigned cur[NPB];
    __shared__ unsigned sh[NPB];
    __shared__ unsigned stage[STAGE_CAP];   // 72 KB
    int tid = threadIdx.x, bb = blockIdx.x;
    if (tid < NPB) deg[tid] = 0;
    __syncthreads();
    unsigned start = bucketPtr[bb], end = bucketPtr[bb + 1];
    unsigned cntE = end - start;
    for (unsigned i = start + tid; i < end; i += 1024)
        atomicAdd(&deg[binned[i] >> 17], 1u);
    __syncthreads();
    unsigned d0 = 0;
    if (tid < NPB) { d0 = deg[tid]; sh[tid] = d0; }
    __syncthreads();
    for (int off = 1; off < NPB; off <<= 1) {
        unsigned v = 0;
        if (tid < NPB && tid >= off) v = sh[tid - off];
        __syncthreads();
        if (tid < NPB) sh[tid] += v;
        __syncthreads();
    }
    if (tid < NPB) {
        unsigned lbase = sh[tid] - d0;        // exclusive prefix (local)
        cur[tid] = lbase;
        int v = (bb << NPB_SHIFT) + tid;
        if (v < n) {
            p0[v] = start + lbase;
            dinv[v] = rsqrtf((float)(d0 + 1u));   // +1 self-loop
        }
    }
    if (bb == 0 && tid == 0) p0[n] = (unsigned)E;
    __syncthreads();
    if (cntE <= STAGE_CAP) {
        for (unsigned i = start + tid; i < end; i += 1024) {
            unsigned entry = binned[i];
            unsigned pos = atomicAdd(&cur[entry >> 17], 1u);
            stage[pos] = entry & 0x1FFFFu;
        }
        __syncthreads();
        for (unsigned i = tid; i < cntE; i += 1024)
            col[start + i] = (int)stage[i];
    } else {
        for (unsigned i = start + tid; i < end; i += 1024) {
            unsigned entry = binned[i];
            unsigned pos = atomicAdd(&cur[entry >> 17], 1u);
            col[start + pos] = (int)(entry & 0x1FFFFu);
        }
    }
}

// g1[v][j] = dinv[v] * (x[v] . W1[:,j]), stored as fp16 (gather table is
// then 3.2 MB -> fits one XCD's 4 MB L2). 16 nodes x 16 feats per block.
__global__ void k_gemm1(const float* __restrict__ x, const float* __restrict__ W1,
                        const float* __restrict__ dinv,
                        h16* __restrict__ g1, int n) {
    __shared__ float w1s[F_IN * F_HID];     // 8 KB
    __shared__ float xs[16][F_IN + 4];
    int tid = threadIdx.x;
    for (int i = tid; i < F_IN * F_HID; i += 256) w1s[i] = W1[i];
    int nb = blockIdx.x * 16;
    for (int q = tid; q < 512; q += 256) {
        int r = q >> 5, k4 = q & 31;
        int g = nb + r;
        float4 v = make_float4(0.f, 0.f, 0.f, 0.f);
        if (g < n) v = ((const float4*)x)[(size_t)g * 32 + k4];
        xs[r][k4 * 4 + 0] = v.x; xs[r][k4 * 4 + 1] = v.y;
        xs[r][k4 * 4 + 2] = v.z; xs[r][k4 * 4 + 3] = v.w;
    }
    __syncthreads();
    int r = tid >> 4, j = tid & 15;
    int g = nb + r;
    if (g < n) {
        float acc = 0.f;
#pragma unroll
        for (int k = 0; k < F_IN; ++k) acc += xs[r][k] * w1s[k * F_HID + j];
        g1[(size_t)g * F_HID + j] = (h16)(acc * dinv[g]);
    }
}

// Pull-mode CSR aggregation: persistent blocks over CONTIGUOUS node chunks
// (locality of r17 + sustained residency of r20). 8 threads/node:
// (sub=0..3) x (q=0..1); each thread gathers a contiguous quarter of the
// node's edges (h16x8 16 B loads; the lane pair's two row halves coalesce
// to ONE 32 B transaction/edge), fp32 accumulate, __shfl_xor masks 2,4.
// 2048 blocks x ~49 contiguous nodes, 32 nodes per round per block ->
// contiguous gout writes (full lines), no second dispatch round.
template <int RELU>
__global__ void __launch_bounds__(256, 8)
k_agg(const unsigned* __restrict__ p0, const int* __restrict__ col,
      const h16x8* __restrict__ gin8, h16x8* __restrict__ gout8,
      const float* __restrict__ dinv, const float* __restrict__ b1, int n) {
    int tid = threadIdx.x;
    int sub = (tid >> 1) & 3;
    int q = tid & 1;
    int npb = (n + gridDim.x - 1) / gridDim.x;          // nodes per block (~49)
    int vbase = blockIdx.x * npb;
    int vend = min(n, vbase + npb);
    for (int v = vbase + (tid >> 3); v < vend; v += 32) {   // 32 nodes/round
        unsigned rs = p0[v], re = p0[v + 1];
        unsigned deg = re - rs;
        unsigned chunk = (deg + 3) >> 2;
        unsigned cs = rs + sub * chunk;
        unsigned ce = min(re, cs + chunk);
        if (cs > re) cs = re;
        f32x8 acc = (f32x8)0.f;
        unsigned i = cs;
        for (; i + 8 <= ce; i += 8) {
            int u0 = __builtin_nontemporal_load(col + i);
            int u1 = __builtin_nontemporal_load(col + i + 1);
            int u2 = __builtin_nontemporal_load(col + i + 2);
            int u3 = __builtin_nontemporal_load(col + i + 3);
            int u4 = __builtin_nontemporal_load(col + i + 4);
            int u5 = __builtin_nontemporal_load(col + i + 5);
            int u6 = __builtin_nontemporal_load(col + i + 6);
            int u7 = __builtin_nontemporal_load(col + i + 7);
            h16x8 a0 = gin8[(size_t)u0 * 2 + q];
            h16x8 a1 = gin8[(size_t)u1 * 2 + q];
            h16x8 a2 = gin8[(size_t)u2 * 2 + q];
            h16x8 a3 = gin8[(size_t)u3 * 2 + q];
            h16x8 a4 = gin8[(size_t)u4 * 2 + q];
            h16x8 a5 = gin8[(size_t)u5 * 2 + q];
            h16x8 a6 = gin8[(size_t)u6 * 2 + q];
            h16x8 a7 = gin8[(size_t)u7 * 2 + q];
            f32x8 s01 = __builtin_convertvector(a0, f32x8) + __builtin_convertvector(a1, f32x8);
            f32x8 s23 = __builtin_convertvector(a2, f32x8) + __builtin_convertvector(a3, f32x8);
            f32x8 s45 = __builtin_convertvector(a4, f32x8) + __builtin_convertvector(a5, f32x8);
            f32x8 s67 = __builtin_convertvector(a6, f32x8) + __builtin_convertvector(a7, f32x8);
            acc += (s01 + s23) + (s45 + s67);
        }
        for (; i < ce; ++i)
            acc += __builtin_convertvector(
                gin8[(size_t)__builtin_nontemporal_load(col + i) * 2 + q], f32x8);
        // combine the 4 sub-partials (lane bits 1,2 within the 8-lane group)
#pragma unroll
        for (int k = 0; k < 8; ++k) acc[k] += __shfl_xor((float)acc[k], 2);
#pragma unroll
        for (int k = 0; k < 8; ++k) acc[k] += __shfl_xor((float)acc[k], 4);
        if (sub == 0) {
            size_t o = (size_t)v * 2 + q;
            acc += __builtin_convertvector(gin8[o], f32x8);   // self-loop
            float di = dinv[v];
            f32x8 r;
            if (RELU) {
                const float* b = b1 + q * 8;
#pragma unroll
                for (int k = 0; k < 8; ++k) r[k] = fmaxf(di * acc[k] + b[k], 0.f) * di;
            } else {
                r = acc * di;
            }
            gout8[o] = __builtin_convertvector(r, h16x8);   // cached: next pass reads it
        }
    }
}

// Node-tiled output GEMM: block owns OUT_NV contiguous nodes; fp16 B rows
// staged once in LDS as fp32, outputs written coalesced NT.
// out[v][c] = B[v] . W2[:,c] + b2[c]   (dinv already folded into B)
__global__ void __launch_bounds__(256)
k_out(const h16* __restrict__ B,
      const float* __restrict__ W2, const float* __restrict__ b2,
      float* __restrict__ out, int n) {
    __shared__ float w2s[F_HID * F_OUT];   // 8.8 KB
    __shared__ float b2s[F_OUT];
    __shared__ float Bs[OUT_NV][F_HID];    // 1 KB
    int tid = threadIdx.x;
    for (int i = tid; i < F_HID * F_OUT; i += 256) w2s[i] = W2[i];
    if (tid < F_OUT) b2s[tid] = b2[tid];
    int vbase = blockIdx.x * OUT_NV;
    {
        int vl = tid >> 4, j = tid & 15;
        int v = vbase + vl;
        Bs[vl][j] = (v < n) ? (float)B[(size_t)v * F_HID + j] : 0.f;
    }
    __syncthreads();
    const int total = OUT_NV * F_OUT;   // 2208
    for (int q = tid; q < total; q += 256) {
        int vl = q / F_OUT, c = q - vl * F_OUT;
        int v = vbase + vl;
        if (v >= n) continue;
        float acc = b2s[c];
#pragma unroll
        for (int j = 0; j < F_HID; ++j) acc += Bs[vl][j] * w2s[j * F_OUT + c];
        __builtin_nontemporal_store(acc, out + (size_t)v * F_OUT + c);
    }
}

extern "C" void kernel_launch(void* const* d_in, const int* in_sizes, int n_in,
                              void* d_out, int out_size, void* d_ws, size_t ws_size,
                              hipStream_t stream) {
    const float* x   = (const float*)d_in[0];
    const int*   idx = (const int*)d_in[1];
    const float* W1  = (const float*)d_in[2];
    const float* b1  = (const float*)d_in[3];
    const float* W2  = (const float*)d_in[4];
    const float* b2  = (const float*)d_in[5];
    float* out = (float*)d_out;

    const int n = in_sizes[0] / F_IN;       // 100000
    const int E = in_sizes[1] / 2;          // 6400000

    char* ws = (char*)d_ws;
    size_t off = 0;
    auto carve = [&](size_t bytes) { char* p = ws + off; off += (bytes + 255) / 256 * 256; return p; };
    float*    dinv      = (float*)carve((size_t)n * 4);
    unsigned* bucketPtr = (unsigned*)carve((NBUCK + 1) * 4);
    unsigned* bucketTot = (unsigned*)carve(NBUCK * 4);
    unsigned* cnt       = (unsigned*)carve((size_t)NBUCK * NB * 4);   // 1 MB
    unsigned* p0        = (unsigned*)carve(((size_t)n + 1) * 4);
    h16*      bufA      = (h16*)carve((size_t)n * F_HID * 2);         // 3.2 MB fp16
    h16*      bufB      = (h16*)carve((size_t)n * F_HID * 2);         // 3.2 MB fp16
    // binned (E words = 25.6 MB) and col (E words) live in d_out (55.2 MB);
    // both fully consumed before k_out overwrites d_out.
    unsigned* binned = (unsigned*)d_out;
    int*      col    = (int*)d_out + (size_t)E;

    const int B = 256;
    k_bincount<<<NB, 1024, 0, stream>>>(idx, cnt, E);
    k_scanA   <<<NBUCK, B, 0, stream>>>(cnt, bucketTot);
    k_scanB   <<<1, NBUCK, 0, stream>>>(bucketTot, bucketPtr);
    k_binfill <<<NB, 1024, 0, stream>>>(idx, cnt, bucketPtr, binned, E);
    k_ptrfill <<<NBUCK, 1024, 0, stream>>>(bucketPtr, binned, p0, dinv, col, n, E);
    k_gemm1   <<<(n + 15) / 16, B, 0, stream>>>(x, W1, dinv, bufA, n);
    // layer 1 (persistent contiguous-chunk pass, fused relu epilogue)
    k_agg<1>  <<<AGG_BLOCKS, B, 0, stream>>>(p0, col, (const h16x8*)bufA,
                                             (h16x8*)bufB, dinv, b1, n);
    // layer 2
    k_agg<0>  <<<AGG_BLOCKS, B, 0, stream>>>(p0, col, (const h16x8*)bufB,
                                             (h16x8*)bufA, dinv, b1, n);
    k_out     <<<(n + OUT_NV - 1) / OUT_NV, B, 0, stream>>>(bufA, W2, b2, out, n);
}

// Round 22
// 222.796 us; speedup vs baseline: 1.0697x; 1.0259x over previous
//
#include <hip/hip_runtime.h>
#include <cstdint>

#define F_IN  128
#define F_HID 16
#define F_OUT 138
#define NBUCK 512        // dst buckets
#define NPB_SHIFT 8
#define NPB 256          // nodes per bucket
#define NB  512          // edge slabs for binning passes
#define SLAB_CAP 12544   // >= ceil(E/NB) = 12500
#define STAGE_CAP 18432  // >= max bucket edges (~16.4k avg + slack)
#define OUT_NV 16        // nodes per k_out block

typedef float f32x8 __attribute__((ext_vector_type(8)));
typedef _Float16 h16;
typedef _Float16 h16x8 __attribute__((ext_vector_type(8)));   // 16 B

// ---------------------------------------------------------------------------
// Inline edge_index dtype detection: int64 (LE, values < 2^31) -> every odd
// int32 word is zero. Returns 2 (int64 stride in words) or 1 (int32).
__device__ __forceinline__ int edge_mult(const int* __restrict__ idx) {
    int nz = 0;
#pragma unroll
    for (int i = 1; i < 64; i += 2) nz |= idx[i];
    return nz ? 1 : 2;
}

// Pass A: per-slab LDS histogram of dst-buckets (reads dst only).
__global__ void __launch_bounds__(1024, 8)
k_bincount(const int* __restrict__ idx, unsigned* __restrict__ cnt, int E) {
    __shared__ unsigned hist[NBUCK];
    int tid = threadIdx.x;
    if (tid < NBUCK) hist[tid] = 0;
    __syncthreads();
    const int mult = edge_mult(idx);
    int slab = (E + NB - 1) / NB;
    int start = blockIdx.x * slab, end = min(E, start + slab);
    if (mult == 2) {
        for (int e = start + tid; e < end; e += 1024)
            atomicAdd(&hist[((const int2*)idx)[(size_t)E + e].x >> NPB_SHIFT], 1u);
    } else {
        for (int e = start + tid; e < end; e += 1024)
            atomicAdd(&hist[idx[(size_t)E + e] >> NPB_SHIFT], 1u);
    }
    __syncthreads();
    if (tid < NBUCK) cnt[(size_t)tid * NB + blockIdx.x] = hist[tid];
}

// Scan step 1: one block per bucket; exclusive-scan its NB slab counts in
// place (pair-per-thread Hillis-Steele); emit bucket total.
__global__ void k_scanA(unsigned* __restrict__ cnt, unsigned* __restrict__ bucketTot) {
    __shared__ unsigned sh[256];
    int t = threadIdx.x;
    unsigned* row = cnt + (size_t)blockIdx.x * NB;
    unsigned e0 = row[2 * t], e1 = row[2 * t + 1];
    unsigned pair = e0 + e1;
    sh[t] = pair;
    __syncthreads();
    for (int off = 1; off < 256; off <<= 1) {
        unsigned v = (t >= off) ? sh[t - off] : 0u;
        __syncthreads();
        sh[t] += v;
        __syncthreads();
    }
    unsigned excl = sh[t] - pair;
    row[2 * t] = excl;
    row[2 * t + 1] = excl + e0;
    if (t == 255) bucketTot[blockIdx.x] = sh[255];
}

// Scan step 2: one block (512 threads); exclusive scan of bucket totals.
__global__ void k_scanB(const unsigned* __restrict__ bucketTot,
                        unsigned* __restrict__ bucketPtr) {
    __shared__ unsigned sh[NBUCK];
    int t = threadIdx.x;
    unsigned c = bucketTot[t];
    sh[t] = c;
    __syncthreads();
    for (int off = 1; off < NBUCK; off <<= 1) {
        unsigned v = (t >= off) ? sh[t - off] : 0u;
        __syncthreads();
        sh[t] += v;
        __syncthreads();
    }
    bucketPtr[t] = sh[t] - c;          // exclusive
    if (t == NBUCK - 1) bucketPtr[NBUCK] = sh[t];
}

// Pass B with LDS write-combining, 1024 threads. Phase-1 histogram is now
// DERIVED from the scanned cnt[] (count(b,s) = cnt[b][s+1]-cnt[b][s], last
// slab via bucketTot) instead of re-reading 51 MB of idx + 12.5M LDS
// atomics. Then: LDS scan -> scatter slab edges into staging sorted by
// bucket -> 16-lane-group copy-out per (slab,bucket) segment.
// Packed entry: (dstLocal<<17) | src  (8+17 = 25 bits, src < 2^17).
__global__ void __launch_bounds__(1024, 8)
k_binfill(const int* __restrict__ idx,
          const unsigned* __restrict__ cnt,
          const unsigned* __restrict__ bucketTot,
          const unsigned* __restrict__ bucketPtr,
          unsigned* __restrict__ binned, int E) {
    __shared__ unsigned hist[NBUCK];
    __shared__ unsigned sofs[NBUCK];
    __shared__ unsigned scur[NBUCK];
    __shared__ unsigned stage[SLAB_CAP];   // 50 KB
    int tid = threadIdx.x;
    // phase 1 (derived): count(b, slab) from scanned cnt
    if (tid < NBUCK) {
        unsigned cbs = cnt[(size_t)tid * NB + blockIdx.x];
        unsigned cnx = (blockIdx.x == NB - 1) ? bucketTot[tid]
                                              : cnt[(size_t)tid * NB + blockIdx.x + 1];
        hist[tid] = cnx - cbs;
    }
    __syncthreads();
    // phase 2: exclusive scan of NBUCK counts (Hillis-Steele on tid<NBUCK)
    if (tid < NBUCK) scur[tid] = hist[tid];
    __syncthreads();
    for (int off = 1; off < NBUCK; off <<= 1) {
        unsigned v = 0;
        if (tid < NBUCK && tid >= off) v = scur[tid - off];
        __syncthreads();
        if (tid < NBUCK) scur[tid] += v;
        __syncthreads();
    }
    if (tid < NBUCK) {
        unsigned ex = scur[tid] - hist[tid];
        sofs[tid] = ex;
        scur[tid] = ex;
    }
    __syncthreads();
    const int mult = edge_mult(idx);
    int slab = (E + NB - 1) / NB;
    int start = blockIdx.x * slab, end = min(E, start + slab);
    // phase 3: scatter slab edges into LDS staging sorted by bucket
    for (int e = start + tid; e < end; e += 1024) {
        int s, d;
        if (mult == 2) { s = ((const int2*)idx)[e].x; d = ((const int2*)idx)[(size_t)E + e].x; }
        else           { s = idx[e];                  d = idx[(size_t)E + e]; }
        unsigned pos = atomicAdd(&scur[d >> NPB_SHIFT], 1u);
        stage[pos] = ((unsigned)(d & (NPB - 1)) << 17) | (unsigned)s;
    }
    __syncthreads();
    // phase 4: copy-out, one 16-lane group per bucket segment
    int g = tid >> 4, lane = tid & 15;       // 64 groups
    for (int b = g; b < NBUCK; b += 64) {
        unsigned s0 = sofs[b], len = scur[b] - s0;
        if (len == 0) continue;
        unsigned gbase = cnt[(size_t)b * NB + blockIdx.x] + bucketPtr[b];
        for (unsigned i = lane; i < len; i += 16)
            binned[gbase + i] = stage[s0 + i];
    }
}

// Fused per-bucket (1024 threads): degree histogram -> scan -> ptr + dinv,
// then sort the bucket's edges into LDS staging by node and stream out
// col[] as one coalesced sequential copy (fallback: direct scatter).
__global__ void __launch_bounds__(1024, 8)
k_ptrfill(const unsigned* __restrict__ bucketPtr,
          const unsigned* __restrict__ binned,
          unsigned* __restrict__ p0,
          float* __restrict__ dinv, int* __restrict__ col,
          int n, int E) {
    __shared__ unsigned deg[NPB];
    __shared__ unsigned cur[NPB];
    __shared__ unsigned sh[NPB];
    __shared__ unsigned stage[STAGE_CAP];   // 72 KB
    int tid = threadIdx.x, bb = blockIdx.x;
    if (tid < NPB) deg[tid] = 0;
    __syncthreads();
    unsigned start = bucketPtr[bb], end = bucketPtr[bb + 1];
    unsigned cntE = end - start;
    for (unsigned i = start + tid; i < end; i += 1024)
        atomicAdd(&deg[binned[i] >> 17], 1u);
    __syncthreads();
    unsigned d0 = 0;
    if (tid < NPB) { d0 = deg[tid]; sh[tid] = d0; }
    __syncthreads();
    for (int off = 1; off < NPB; off <<= 1) {
        unsigned v = 0;
        if (tid < NPB && tid >= off) v = sh[tid - off];
        __syncthreads();
        if (tid < NPB) sh[tid] += v;
        __syncthreads();
    }
    if (tid < NPB) {
        unsigned lbase = sh[tid] - d0;        // exclusive prefix (local)
        cur[tid] = lbase;
        int v = (bb << NPB_SHIFT) + tid;
        if (v < n) {
            p0[v] = start + lbase;
            dinv[v] = rsqrtf((float)(d0 + 1u));   // +1 self-loop
        }
    }
    if (bb == 0 && tid == 0) p0[n] = (unsigned)E;
    __syncthreads();
    if (cntE <= STAGE_CAP) {
        for (unsigned i = start + tid; i < end; i += 1024) {
            unsigned entry = binned[i];
            unsigned pos = atomicAdd(&cur[entry >> 17], 1u);
            stage[pos] = entry & 0x1FFFFu;
        }
        __syncthreads();
        for (unsigned i = tid; i < cntE; i += 1024)
            col[start + i] = (int)stage[i];
    } else {
        for (unsigned i = start + tid; i < end; i += 1024) {
            unsigned entry = binned[i];
            unsigned pos = atomicAdd(&cur[entry >> 17], 1u);
            col[start + pos] = (int)(entry & 0x1FFFFu);
        }
    }
}

// g1[v][j] = dinv[v] * (x[v] . W1[:,j]), stored as fp16 (gather table is
// then 3.2 MB -> fits one XCD's 4 MB L2). 16 nodes x 16 feats per block.
__global__ void k_gemm1(const float* __restrict__ x, const float* __restrict__ W1,
                        const float* __restrict__ dinv,
                        h16* __restrict__ g1, int n) {
    __shared__ float w1s[F_IN * F_HID];     // 8 KB
    __shared__ float xs[16][F_IN + 4];
    int tid = threadIdx.x;
    for (int i = tid; i < F_IN * F_HID; i += 256) w1s[i] = W1[i];
    int nb = blockIdx.x * 16;
    for (int q = tid; q < 512; q += 256) {
        int r = q >> 5, k4 = q & 31;
        int g = nb + r;
        float4 v = make_float4(0.f, 0.f, 0.f, 0.f);
        if (g < n) v = ((const float4*)x)[(size_t)g * 32 + k4];
        xs[r][k4 * 4 + 0] = v.x; xs[r][k4 * 4 + 1] = v.y;
        xs[r][k4 * 4 + 2] = v.z; xs[r][k4 * 4 + 3] = v.w;
    }
    __syncthreads();
    int r = tid >> 4, j = tid & 15;
    int g = nb + r;
    if (g < n) {
        float acc = 0.f;
#pragma unroll
        for (int k = 0; k < F_IN; ++k) acc += xs[r][k] * w1s[k * F_HID + j];
        g1[(size_t)g * F_HID + j] = (h16)(acc * dinv[g]);
    }
}

// Pull-mode CSR aggregation — EXACT r17 structure (measured best: 58 us,
// FETCH 53 MB). 8 threads/node: (sub=0..3) x (q=0..1); each thread gathers
// a contiguous quarter of the node's edges (h16x8 16 B loads; the lane
// pair's two row halves coalesce to ONE 32 B transaction/edge), fp32
// accumulate, combine via __shfl_xor masks 2,4. sub==0 adds self-loop,
// applies epilogue, stores fp16.
template <int RELU>
__global__ void __launch_bounds__(256)
k_agg(const unsigned* __restrict__ p0, const int* __restrict__ col,
      const h16x8* __restrict__ gin8, h16x8* __restrict__ gout8,
      const float* __restrict__ dinv, const float* __restrict__ b1, int n) {
    int t = blockIdx.x * blockDim.x + threadIdx.x;
    int v = t >> 3;
    int sub = (t >> 1) & 3;
    int q = t & 1;
    if (v >= n) return;
    unsigned rs = p0[v], re = p0[v + 1];
    unsigned deg = re - rs;
    unsigned chunk = (deg + 3) >> 2;
    unsigned cs = rs + sub * chunk;
    unsigned ce = min(re, cs + chunk);
    if (cs > re) cs = re;
    f32x8 acc = (f32x8)0.f;
    unsigned i = cs;
    for (; i + 8 <= ce; i += 8) {
        int u0 = __builtin_nontemporal_load(col + i);
        int u1 = __builtin_nontemporal_load(col + i + 1);
        int u2 = __builtin_nontemporal_load(col + i + 2);
        int u3 = __builtin_nontemporal_load(col + i + 3);
        int u4 = __builtin_nontemporal_load(col + i + 4);
        int u5 = __builtin_nontemporal_load(col + i + 5);
        int u6 = __builtin_nontemporal_load(col + i + 6);
        int u7 = __builtin_nontemporal_load(col + i + 7);
        h16x8 a0 = gin8[(size_t)u0 * 2 + q];
        h16x8 a1 = gin8[(size_t)u1 * 2 + q];
        h16x8 a2 = gin8[(size_t)u2 * 2 + q];
        h16x8 a3 = gin8[(size_t)u3 * 2 + q];
        h16x8 a4 = gin8[(size_t)u4 * 2 + q];
        h16x8 a5 = gin8[(size_t)u5 * 2 + q];
        h16x8 a6 = gin8[(size_t)u6 * 2 + q];
        h16x8 a7 = gin8[(size_t)u7 * 2 + q];
        f32x8 s01 = __builtin_convertvector(a0, f32x8) + __builtin_convertvector(a1, f32x8);
        f32x8 s23 = __builtin_convertvector(a2, f32x8) + __builtin_convertvector(a3, f32x8);
        f32x8 s45 = __builtin_convertvector(a4, f32x8) + __builtin_convertvector(a5, f32x8);
        f32x8 s67 = __builtin_convertvector(a6, f32x8) + __builtin_convertvector(a7, f32x8);
        acc += (s01 + s23) + (s45 + s67);
    }
    for (; i < ce; ++i)
        acc += __builtin_convertvector(
            gin8[(size_t)__builtin_nontemporal_load(col + i) * 2 + q], f32x8);
    // combine the 4 sub-partials (lane bits 1,2 within the 8-lane node group)
#pragma unroll
    for (int k = 0; k < 8; ++k) acc[k] += __shfl_xor((float)acc[k], 2);
#pragma unroll
    for (int k = 0; k < 8; ++k) acc[k] += __shfl_xor((float)acc[k], 4);
    if (sub == 0) {
        size_t o = (size_t)v * 2 + q;
        acc += __builtin_convertvector(gin8[o], f32x8);   // self-loop
        float di = dinv[v];
        f32x8 r;
        if (RELU) {
            const float* b = b1 + q * 8;
#pragma unroll
            for (int k = 0; k < 8; ++k) r[k] = fmaxf(di * acc[k] + b[k], 0.f) * di;
        } else {
            r = acc * di;
        }
        gout8[o] = __builtin_convertvector(r, h16x8);   // cached: next pass reads it
    }
}

// Node-tiled output GEMM: block owns OUT_NV contiguous nodes; fp16 B rows
// staged once in LDS as fp32, outputs written coalesced NT.
// out[v][c] = B[v] . W2[:,c] + b2[c]   (dinv already folded into B)
__global__ void __launch_bounds__(256)
k_out(const h16* __restrict__ B,
      const float* __restrict__ W2, const float* __restrict__ b2,
      float* __restrict__ out, int n) {
    __shared__ float w2s[F_HID * F_OUT];   // 8.8 KB
    __shared__ float b2s[F_OUT];
    __shared__ float Bs[OUT_NV][F_HID];    // 1 KB
    int tid = threadIdx.x;
    for (int i = tid; i < F_HID * F_OUT; i += 256) w2s[i] = W2[i];
    if (tid < F_OUT) b2s[tid] = b2[tid];
    int vbase = blockIdx.x * OUT_NV;
    {
        int vl = tid >> 4, j = tid & 15;
        int v = vbase + vl;
        Bs[vl][j] = (v < n) ? (float)B[(size_t)v * F_HID + j] : 0.f;
    }
    __syncthreads();
    const int total = OUT_NV * F_OUT;   // 2208
    for (int q = tid; q < total; q += 256) {
        int vl = q / F_OUT, c = q - vl * F_OUT;
        int v = vbase + vl;
        if (v >= n) continue;
        float acc = b2s[c];
#pragma unroll
        for (int j = 0; j < F_HID; ++j) acc += Bs[vl][j] * w2s[j * F_OUT + c];
        __builtin_nontemporal_store(acc, out + (size_t)v * F_OUT + c);
    }
}

extern "C" void kernel_launch(void* const* d_in, const int* in_sizes, int n_in,
                              void* d_out, int out_size, void* d_ws, size_t ws_size,
                              hipStream_t stream) {
    const float* x   = (const float*)d_in[0];
    const int*   idx = (const int*)d_in[1];
    const float* W1  = (const float*)d_in[2];
    const float* b1  = (const float*)d_in[3];
    const float* W2  = (const float*)d_in[4];
    const float* b2  = (const float*)d_in[5];
    float* out = (float*)d_out;

    const int n = in_sizes[0] / F_IN;       // 100000
    const int E = in_sizes[1] / 2;          // 6400000

    char* ws = (char*)d_ws;
    size_t off = 0;
    auto carve = [&](size_t bytes) { char* p = ws + off; off += (bytes + 255) / 256 * 256; return p; };
    float*    dinv      = (float*)carve((size_t)n * 4);
    unsigned* bucketPtr = (unsigned*)carve((NBUCK + 1) * 4);
    unsigned* bucketTot = (unsigned*)carve(NBUCK * 4);
    unsigned* cnt       = (unsigned*)carve((size_t)NBUCK * NB * 4);   // 1 MB
    unsigned* p0        = (unsigned*)carve(((size_t)n + 1) * 4);
    h16*      bufA      = (h16*)carve((size_t)n * F_HID * 2);         // 3.2 MB fp16
    h16*      bufB      = (h16*)carve((size_t)n * F_HID * 2);         // 3.2 MB fp16
    // binned (E words = 25.6 MB) and col (E words) live in d_out (55.2 MB);
    // both fully consumed before k_out overwrites d_out.
    unsigned* binned = (unsigned*)d_out;
    int*      col    = (int*)d_out + (size_t)E;

    const int B = 256;
    const int nbAgg8 = (n * 8 + B - 1) / B;   // 3125
    k_bincount<<<NB, 1024, 0, stream>>>(idx, cnt, E);
    k_scanA   <<<NBUCK, B, 0, stream>>>(cnt, bucketTot);
    k_scanB   <<<1, NBUCK, 0, stream>>>(bucketTot, bucketPtr);
    k_binfill <<<NB, 1024, 0, stream>>>(idx, cnt, bucketTot, bucketPtr, binned, E);
    k_ptrfill <<<NBUCK, 1024, 0, stream>>>(bucketPtr, binned, p0, dinv, col, n, E);
    k_gemm1   <<<(n + 15) / 16, B, 0, stream>>>(x, W1, dinv, bufA, n);
    // layer 1 (edge-split pass, fused relu epilogue)
    k_agg<1>  <<<nbAgg8, B, 0, stream>>>(p0, col, (const h16x8*)bufA,
                                         (h16x8*)bufB, dinv, b1, n);
    // layer 2
    k_agg<0>  <<<nbAgg8, B, 0, stream>>>(p0, col, (const h16x8*)bufB,
                                         (h16x8*)bufA, dinv, b1, n);
    k_out     <<<(n + OUT_NV - 1) / OUT_NV, B, 0, stream>>>(bufA, W2, b2, out, n);
}